// Round 12
// baseline (1064.174 us; speedup 1.0000x reference)
//
#include <hip/hip_runtime.h>
#include <math.h>

// Problem constants
constexpr int Dc = 128;   // channels
constexpr int Kc = 512;   // codebook entries
constexpr int Bc = 8;     // batch

// ---------------------------------------------------------------------------
// LDS-tiled layer kernel: conv (ISADD=0) or AdderNet L1 (ISADD=1).
// Block = 256 threads = 4 waves; covers OUT_ROWS x WOUT pixels x 4*COBW output
// channels (COBW per wave, lane = PW-pixel group). Channel loop software-
// pipelined: chunk c+1 staged into REGISTERS before chunk c's compute, then
// written to LDS post-barrier.
// Staging mode by PAD alignment:
//   PAD%4==0 : float4 loads, float4-at-aligned-col writes (merge to b128).
//   else     : b32 loads with lane-consecutive columns -> LDS writes cover
//              all 32 banks at min phase (ZERO bank conflicts; the float4
//              ownership pattern only touched banks == PAD mod 4 + 4Z,
//              an 8-way conflict measured at 2.4e7 cycles on we2 in R9).
// Reads are vectorized+aligned (SPAN=6 -> b128+b64, 4 -> 2xb64, 2 -> b64),
// provably min-phase on the 32 banks.
//
// IT: 0 none, 1 relu, 2 relu(bn) with itG/itB
// EPI (val = -acc adder / acc conv): 1 relu(bn_o(val)); 2 res+val;
//   3 bn_r(res)+val; 5 relu(val); 6 bn_o(bn_r(res)+val)
template<int ISADD, int K, int STRIDE, int PAD, int IT, int EPI, int CIN, int CH,
         int OUT_ROWS, int WOUT, int WIN, int HIN, int HOUT, int COBW>
__global__ __launch_bounds__(256)
void lds_layer(const float* __restrict__ x, const float* __restrict__ w,
               const float* __restrict__ bias,
               const float* __restrict__ itG, const float* __restrict__ itB,
               const float* __restrict__ res,
               const float* __restrict__ rG, const float* __restrict__ rB,
               const float* __restrict__ oG, const float* __restrict__ oB,
               float* __restrict__ out) {
  constexpr int PW = (OUT_ROWS * WOUT) / 64;    // pixels per lane
  constexpr int KK = K * K;
  constexpr int SPAN = (PW - 1) * STRIDE + K;
  constexpr int IN_ROWS = (OUT_ROWS - 1) * STRIDE + K;
  constexpr int WPAD = (WOUT - 1) * STRIDE + K;
  constexpr int WLDS = (WPAD + 3) & ~3;         // mult of 4: aligned vector reads
  constexpr int PGW = WOUT / PW;
  static_assert(OUT_ROWS * PGW == 64, "one wave covers the pixel tile");
  constexpr int NCG = Dc / (4 * COBW);
  constexpr int NBAND = HOUT / OUT_ROWS;
  constexpr bool B32S = (PAD % 4) != 0;         // conflict-free b32 staging
  constexpr int W4 = WIN / 4;
  constexpr int NELEM4 = CH * IN_ROWS * W4;     // float4 path
  constexpr int NIT4 = (NELEM4 + 255) / 256;
  constexpr bool EXACT4 = (NELEM4 % 256) == 0;
  constexpr int NELEM1 = CH * IN_ROWS * WIN;    // b32 path
  static_assert(!B32S || (NELEM1 % 256) == 0, "b32 staging divides block");
  constexpr int NIT1 = NELEM1 / 256;
  constexpr int NIT = B32S ? NIT1 : NIT4;
  const float r15 = rsqrtf(1.0f + 1e-5f);

  __shared__ alignas(16) float lds[CH][IN_ROWS][WLDS];

  int tid = threadIdx.x;
  int gb = blockIdx.x;
  // XCD swizzle: cg outermost -> all channel-groups of a band share an XCD L2.
  int cg = gb / (Bc * NBAND);
  int rem = gb % (Bc * NBAND);
  int band = rem % NBAND;
  int b = rem / NBAND;
  int wv = __builtin_amdgcn_readfirstlane(tid >> 6);
  int lane = tid & 63;
  int co0 = cg * (4 * COBW) + wv * COBW;
  int pr = lane / PGW, pc = lane % PGW;
  int oh = band * OUT_ROWS + pr;
  int ow0 = pc * PW;
  int yi0 = band * OUT_ROWS * STRIDE - PAD;

  // zero LDS once: pad columns stay zero forever
  for (int e = tid; e < CH * IN_ROWS * WLDS; e += 256) ((float*)lds)[e] = 0.f;

  float acc[PW][COBW];
#pragma unroll
  for (int p = 0; p < PW; ++p)
#pragma unroll
    for (int j = 0; j < COBW; ++j)
      acc[p][j] = ISADD ? 0.f : bias[co0 + j];

  const float* xb = x + (long)b * CIN * HIN * WIN;
  float4 rbuf4[B32S ? 1 : NIT4];
  float  rbuf1[B32S ? NIT1 : 1];

  auto stage = [&](int c0) {
    if constexpr (B32S) {
#pragma unroll
      for (int it = 0; it < NIT1; ++it) {
        int e = it * 256 + tid;
        int col = e % WIN;                       // lane-consecutive columns
        int r = (e / WIN) % IN_ROWS;
        int ch = e / (WIN * IN_ROWS);
        int yi = yi0 + r;
        float v = 0.f;
        if (yi >= 0 && yi < HIN) {
          v = xb[((long)(c0 + ch) * HIN + yi) * WIN + col];
          if (IT == 1) v = fmaxf(v, 0.f);
          if (IT == 2) v = fmaxf(fmaf(v, itG[c0 + ch] * r15, itB[c0 + ch]), 0.f);
        }
        rbuf1[it] = v;
      }
    } else {
#pragma unroll
      for (int it = 0; it < NIT4; ++it) {
        int e = it * 256 + tid;
        if (!EXACT4 && e >= NELEM4) break;
        int c4 = e % W4;
        int r = (e / W4) % IN_ROWS;
        int ch = e / (W4 * IN_ROWS);
        int yi = yi0 + r;
        float4 v = make_float4(0.f, 0.f, 0.f, 0.f);
        if (yi >= 0 && yi < HIN) {
          v = *(const float4*)&xb[((long)(c0 + ch) * HIN + yi) * WIN + 4 * c4];
          if (IT == 1) {
            v.x = fmaxf(v.x, 0.f); v.y = fmaxf(v.y, 0.f);
            v.z = fmaxf(v.z, 0.f); v.w = fmaxf(v.w, 0.f);
          }
          if (IT == 2) {
            float sc = itG[c0 + ch] * r15, bc = itB[c0 + ch];
            v.x = fmaxf(fmaf(v.x, sc, bc), 0.f);
            v.y = fmaxf(fmaf(v.y, sc, bc), 0.f);
            v.z = fmaxf(fmaf(v.z, sc, bc), 0.f);
            v.w = fmaxf(fmaf(v.w, sc, bc), 0.f);
          }
        }
        rbuf4[it] = v;
      }
    }
  };
  auto towrite = [&]() {
    if constexpr (B32S) {
#pragma unroll
      for (int it = 0; it < NIT1; ++it) {
        int e = it * 256 + tid;
        int col = e % WIN;
        int r = (e / WIN) % IN_ROWS;
        int ch = e / (WIN * IN_ROWS);
        lds[ch][r][col + PAD] = rbuf1[it];      // all 32 banks, min phase
      }
    } else {
#pragma unroll
      for (int it = 0; it < NIT4; ++it) {
        int e = it * 256 + tid;
        if (!EXACT4 && e >= NELEM4) break;
        int c4 = e % W4;
        int r = (e / W4) % IN_ROWS;
        int ch = e / (W4 * IN_ROWS);
        float* p = &lds[ch][r][4 * c4 + PAD];   // PAD%4==0: merges to b128
        float4 v = rbuf4[it];
        p[0] = v.x; p[1] = v.y; p[2] = v.z; p[3] = v.w;
      }
    }
  };

  stage(0);
  for (int c0 = 0; c0 < CIN; c0 += CH) {
    __syncthreads();           // previous compute done before LDS overwrite
    towrite();
    __syncthreads();           // all writes visible
    if (c0 + CH < CIN) stage(c0 + CH);   // loads overlap compute below
    for (int ch = 0; ch < CH; ++ch) {
      float vbuf[K][SPAN];
#pragma unroll
      for (int kh = 0; kh < K; ++kh) {
        const float* rp0 = &lds[ch][pr * STRIDE + kh][ow0 * STRIDE];
        if constexpr (SPAN == 6 && (PW * STRIDE) % 4 == 0) {
          float4 a = *(const float4*)rp0;            // 16B aligned: col=4*pc
          float2 c2 = *(const float2*)(rp0 + 4);
          vbuf[kh][0] = a.x; vbuf[kh][1] = a.y; vbuf[kh][2] = a.z;
          vbuf[kh][3] = a.w; vbuf[kh][4] = c2.x; vbuf[kh][5] = c2.y;
        } else if constexpr (SPAN == 4 && (PW * STRIDE) % 2 == 0) {
          float2 a = *(const float2*)rp0;            // 8B aligned: col=2*pc
          float2 c2 = *(const float2*)(rp0 + 2);
          vbuf[kh][0] = a.x; vbuf[kh][1] = a.y;
          vbuf[kh][2] = c2.x; vbuf[kh][3] = c2.y;
        } else if constexpr (SPAN == 2 && (PW * STRIDE) % 2 == 0) {
          float2 a = *(const float2*)rp0;
          vbuf[kh][0] = a.x; vbuf[kh][1] = a.y;
        } else {
#pragma unroll
          for (int s = 0; s < SPAN; ++s) vbuf[kh][s] = rp0[s];
        }
      }
      const float* wc = w + ((long)co0 * CIN + (c0 + ch)) * KK;
#pragma unroll
      for (int kh = 0; kh < K; ++kh)
#pragma unroll
        for (int kw = 0; kw < K; ++kw)
#pragma unroll
          for (int j = 0; j < COBW; ++j) {
            float ww = wc[(long)j * CIN * KK + kh * K + kw];
#pragma unroll
            for (int p = 0; p < PW; ++p) {
              float v = vbuf[kh][p * STRIDE + kw];
              if (ISADD) acc[p][j] += fabsf(v - ww);
              else       acc[p][j] = fmaf(v, ww, acc[p][j]);
            }
          }
    }
  }

  // ---- epilogue ----
  long obase = ((long)(b * Dc + co0) * HOUT + oh) * WOUT + ow0;
  float* ob = out + obase;
  const float* rp = (EPI == 2 || EPI == 3 || EPI == 6) ? res + obase : nullptr;
  constexpr long hw = (long)HOUT * WOUT;
#pragma unroll
  for (int j = 0; j < COBW; ++j) {
    float og = 0.f, obb = 0.f, rg = 0.f, rbb = 0.f;
    if (EPI == 1 || EPI == 6) { og = oG[co0 + j] * r15; obb = oB[co0 + j]; }
    if (EPI == 3 || EPI == 6) { rg = rG[co0 + j] * r15; rbb = rB[co0 + j]; }
#pragma unroll
    for (int p = 0; p < PW; ++p) {
      float val = ISADD ? -acc[p][j] : acc[p][j];
      if (EPI == 1) val = fmaxf(fmaf(val, og, obb), 0.f);
      if (EPI == 2) val = rp[j * hw + p] + val;
      if (EPI == 3) val = fmaf(rp[j * hw + p], rg, rbb) + val;
      if (EPI == 5) val = fmaxf(val, 0.f);
      if (EPI == 6) val = fmaf(fmaf(rp[j * hw + p], rg, rbb) + val, og, obb);
      ob[j * hw + p] = val;
    }
  }
}

// ---------------------------------------------------------------------------
// 2x bilinear upsample, align_corners=False (clamped, weights 0.25/0.75)
__device__ __forceinline__ void up_coef(int p, int H, int& i0, int& i1, float& w0, float& w1) {
  int m = p >> 1;
  if ((p & 1) == 0) { i0 = (m > 0) ? m - 1 : 0; i1 = m; w0 = 0.25f; w1 = 0.75f; }
  else              { i0 = m; i1 = (m + 1 < H) ? m + 1 : H - 1; w0 = 0.75f; w1 = 0.25f; }
}

__global__ void up2x_kernel(const float* __restrict__ in, float* __restrict__ out,
                            int C, int H, int W) {
  int H2 = 2 * H, W2 = 2 * W;
  int i = blockIdx.x * blockDim.x + threadIdx.x;
  int total = Bc * C * H2 * W2;
  if (i >= total) return;
  int ow = i % W2; int t = i / W2;
  int oh = t % H2; t /= H2;
  int c = t % C; int b = t / C;
  int y0, y1, x0, x1; float wy0, wy1, wx0, wx1;
  up_coef(oh, H, y0, y1, wy0, wy1);
  up_coef(ow, W, x0, x1, wx0, wx1);
  const float* p = in + (b * C + c) * H * W;
  float v = wy0 * (wx0 * p[y0 * W + x0] + wx1 * p[y0 * W + x1])
          + wy1 * (wx0 * p[y1 * W + x0] + wx1 * p[y1 * W + x1]);
  out[i] = v;
}

// ---------------------------------------------------------------------------
// Fused: up2x -> conv3x3(128->Cout, pad=1) -> +bias -> tanh. One thread = one
// (b, co, 2x2 output quad).
__global__ __launch_bounds__(256)
void conv3x3_up_tanh_quad(const float* __restrict__ x, const float* __restrict__ w,
                          const float* __restrict__ bias, float* __restrict__ out,
                          int Hs, int Ws, int Cout) {
  constexpr int CIN = Dc;
  int H2 = 2 * Hs, W2 = 2 * Ws;
  int nq = Hs * Ws;
  int i = blockIdx.x * blockDim.x + threadIdx.x;
  int total = Bc * Cout * nq;
  if (i >= total) return;
  int q = i % nq; int t = i / nq;
  int co = t % Cout; int b = t / Cout;
  int n = q % Ws, m = q / Ws;
  int rows[3] = { (m > 0) ? m - 1 : 0, m, (m + 1 < Hs) ? m + 1 : Hs - 1 };
  int cols[3] = { (n > 0) ? n - 1 : 0, n, (n + 1 < Ws) ? n + 1 : Ws - 1 };
  float rv[4] = { (2 * m - 1 >= 0) ? 1.f : 0.f, 1.f, 1.f, (2 * m + 2 < H2) ? 1.f : 0.f };
  float cv[4] = { (2 * n - 1 >= 0) ? 1.f : 0.f, 1.f, 1.f, (2 * n + 2 < W2) ? 1.f : 0.f };
  float bco = bias[co];
  float acc[4] = { bco, bco, bco, bco };
  const float* xb = x + b * CIN * nq;
  const float* wb = w + co * CIN * 9;
  for (int c = 0; c < CIN; ++c) {
    const float* xc = xb + c * nq;
    float s[3][3];
#pragma unroll
    for (int a = 0; a < 3; ++a)
#pragma unroll
      for (int e = 0; e < 3; ++e) s[a][e] = xc[rows[a] * Ws + cols[e]];
    float rb[4][3];
#pragma unroll
    for (int e = 0; e < 3; ++e) {
      rb[0][e] = fmaf(0.75f, s[0][e], 0.25f * s[1][e]);
      rb[1][e] = fmaf(0.25f, s[0][e], 0.75f * s[1][e]);
      rb[2][e] = fmaf(0.75f, s[1][e], 0.25f * s[2][e]);
      rb[3][e] = fmaf(0.25f, s[1][e], 0.75f * s[2][e]);
    }
    float u[4][4];
#pragma unroll
    for (int di = 0; di < 4; ++di) {
      float rm = rv[di];
      u[di][0] = fmaf(0.75f, rb[di][0], 0.25f * rb[di][1]) * rm * cv[0];
      u[di][1] = fmaf(0.25f, rb[di][0], 0.75f * rb[di][1]) * rm * cv[1];
      u[di][2] = fmaf(0.75f, rb[di][1], 0.25f * rb[di][2]) * rm * cv[2];
      u[di][3] = fmaf(0.25f, rb[di][1], 0.75f * rb[di][2]) * rm * cv[3];
    }
    const float* wc = wb + c * 9;
#pragma unroll
    for (int kh = 0; kh < 3; ++kh)
#pragma unroll
      for (int kw = 0; kw < 3; ++kw) {
        float ww = wc[kh * 3 + kw];
        acc[0] = fmaf(u[kh][kw],         ww, acc[0]);
        acc[1] = fmaf(u[kh][kw + 1],     ww, acc[1]);
        acc[2] = fmaf(u[kh + 1][kw],     ww, acc[2]);
        acc[3] = fmaf(u[kh + 1][kw + 1], ww, acc[3]);
      }
  }
  float* ob = out + (b * Cout + co) * H2 * W2 + (2 * m) * W2 + 2 * n;
  ob[0] = tanhf(acc[0]);      ob[1] = tanhf(acc[1]);
  ob[W2] = tanhf(acc[2]);     ob[W2 + 1] = tanhf(acc[3]);
}

// ---------------------------------------------------------------------------
// VQ: precompute |E_k|^2 (d ascending, same as reference)
__global__ void vq_e2_kernel(const float* __restrict__ E, float* __restrict__ e2) {
  int k = blockIdx.x * blockDim.x + threadIdx.x;
  if (k >= Kc) return;
  float s = 0.f;
  for (int d = 0; d < Dc; ++d) { float v = E[d * Kc + k]; s += v * v; }
  e2[k] = s;
}

// VQ nearest-embedding: one 256-thread block per 8 spatial points.
__global__ __launch_bounds__(256)
void vq_kernel8(const float* __restrict__ z_e, const float* __restrict__ E,
                const float* __restrict__ e2,
                float* __restrict__ emb, float* __restrict__ argmin_out) {
  constexpr int HW = 1024;
  __shared__ float f[8][Dc];
  __shared__ float d2s[8][256];
  __shared__ int   ks[8][256];
  int tid = threadIdx.x;
  int n0 = blockIdx.x * 8;
  int b = n0 >> 10;
  int rem = n0 & 1023;
  const float* zb = z_e + (long)b * Dc * HW + rem;
#pragma unroll
  for (int i = 0; i < 4; ++i) {
    int e = i * 256 + tid;
    int p = e & 7, d = e >> 3;
    f[p][d] = zb[d * HW + p];
  }
  __syncthreads();
  float f2 = 0.f;
  if (tid < 8) {
    for (int d = 0; d < Dc; ++d) f2 += f[tid][d] * f[tid][d];
    d2s[tid][0] = f2;
  }
  __syncthreads();
  float f2v[8];
#pragma unroll
  for (int p = 0; p < 8; ++p) f2v[p] = d2s[p][0];
  __syncthreads();

  float best[8]; int bk[8];
#pragma unroll
  for (int p = 0; p < 8; ++p) { best[p] = 3.4e38f; bk[p] = 0; }
  for (int kk = tid; kk < Kc; kk += 256) {
    float dot[8];
#pragma unroll
    for (int p = 0; p < 8; ++p) dot[p] = 0.f;
    for (int d = 0; d < Dc; ++d) {
      float ed = E[d * Kc + kk];
#pragma unroll
      for (int p = 0; p < 8; ++p) dot[p] = fmaf(f[p][d], ed, dot[p]);
    }
    float e2k = e2[kk];
#pragma unroll
    for (int p = 0; p < 8; ++p) {
      float d2 = f2v[p] - 2.f * dot[p] + e2k;
      if (d2 < best[p] || (d2 == best[p] && kk < bk[p])) { best[p] = d2; bk[p] = kk; }
    }
  }
#pragma unroll
  for (int p = 0; p < 8; ++p) { d2s[p][tid] = best[p]; ks[p][tid] = bk[p]; }
  __syncthreads();
  for (int s = 128; s > 0; s >>= 1) {
    if (tid < s) {
#pragma unroll
      for (int p = 0; p < 8; ++p) {
        float ob = d2s[p][tid + s]; int ok = ks[p][tid + s];
        if (ob < d2s[p][tid] || (ob == d2s[p][tid] && ok < ks[p][tid])) {
          d2s[p][tid] = ob; ks[p][tid] = ok;
        }
      }
    }
    __syncthreads();
  }
  if (tid < 8) argmin_out[n0 + tid] = (float)ks[tid][0];
  float* eb = emb + (long)b * Dc * HW + rem;
#pragma unroll
  for (int i = 0; i < 4; ++i) {
    int e = i * 256 + tid;
    int p = e & 7, d = e >> 3;
    eb[d * HW + p] = E[d * Kc + ks[p][0]];
  }
}

// ---------------------------------------------------------------------------
extern "C" void kernel_launch(void* const* d_in, const int* in_sizes, int n_in,
                              void* d_out, int out_size, void* d_ws, size_t ws_size,
                              hipStream_t stream) {
  const float* x      = (const float*)d_in[0];
  const float* we1    = (const float*)d_in[1];
  const float* we2    = (const float*)d_in[2];
  const float* ae1_w1 = (const float*)d_in[3];
  const float* ae1_w2 = (const float*)d_in[4];
  const float* ae2_w1 = (const float*)d_in[5];
  const float* ae2_w2 = (const float*)d_in[6];
  const float* bn_g   = (const float*)d_in[7];   // [8,128]
  const float* bn_b   = (const float*)d_in[8];
  const float* embw   = (const float*)d_in[9];   // [128,512]
  const float* rd1_w1 = (const float*)d_in[10];
  const float* rd1_b1 = (const float*)d_in[11];
  const float* rd1_w2 = (const float*)d_in[12];
  const float* rd1_b2 = (const float*)d_in[13];
  const float* rd2_w1 = (const float*)d_in[14];
  const float* rd2_b1 = (const float*)d_in[15];
  const float* rd2_w2 = (const float*)d_in[16];
  const float* rd2_b2 = (const float*)d_in[17];
  const float* cd1_w  = (const float*)d_in[18];
  const float* cd1_b  = (const float*)d_in[19];
  const float* cd2_w  = (const float*)d_in[20];
  const float* cd2_b  = (const float*)d_in[21];

  const float* g0 = bn_g + 0 * Dc; const float* b0 = bn_b + 0 * Dc;
  const float* g1 = bn_g + 1 * Dc; const float* b1 = bn_b + 1 * Dc;
  const float* g2 = bn_g + 2 * Dc; const float* b2 = bn_b + 2 * Dc;
  const float* g3 = bn_g + 3 * Dc; const float* b3 = bn_b + 3 * Dc;
  const float* g4 = bn_g + 4 * Dc; const float* b4 = bn_b + 4 * Dc;
  const float* g5 = bn_g + 5 * Dc; const float* b5 = bn_b + 5 * Dc;
  const float* g6 = bn_g + 6 * Dc; const float* b6 = bn_b + 6 * Dc;
  const float* g7 = bn_g + 7 * Dc; const float* b7 = bn_b + 7 * Dc;

  // Workspace: two 64x64 buffers + three 32x32 buffers
  float* W64a = (float*)d_ws;            // [8,128,64,64]
  float* W64b = W64a + 4194304;          // [8,128,64,64]
  float* Wa   = W64b + 4194304;          // [8,128,32,32]
  float* Wb   = Wa + 1048576;
  float* Wc   = Wb + 1048576;
  float* e2b  = W64b;                    // 512 floats, free until cd1 writes W64b

  // Output layout: y | z_e | emb | argmin
  float* out_y   = (float*)d_out;        // 8*3*128*128
  float* out_ze  = out_y  + 393216;      // 8*128*32*32
  float* out_emb = out_ze + 1048576;
  float* out_am  = out_emb + 1048576;

  const int TB = 256;
  auto nb = [](int n) { return (n + 255) / 256; };
  const int N64 = Bc * Dc * 64 * 64;
  const float* nul = nullptr;

  // grids: NCG * Bc * NBAND  (R9 configs)
  const int G32c2 = 16 * Bc * 8;         // 1024 (32x32, OUT_ROWS=4 -> PW=2, COBW=2)
  const int G32c4 = 8 * Bc * 8;          // 512  (32x32, OUT_ROWS=4 -> PW=2, COBW=4)
  const int G64c4 = 8 * Bc * 32;         // 2048 (64x64, OUT_ROWS=2 -> PW=2, COBW=4)
  const int G64c8 = 4 * Bc * 32;         // 1024 (64x64, OUT_ROWS=2 -> PW=2, COBW=8)

  // ---------------- encoder ----------------
  // we1: adder 4x4 s2, 3ch (single chunk), 128->64; epi relu(bn0)
  lds_layer<1,4,2,1, 0,1, 3,3, 2,64,128,128,64, 4><<<G64c4, TB, 0, stream>>>(
      x, we1, nul, nul, nul, nul, nul, nul, g0, b0, W64a);
  // we2: adder 4x4 s2, 64->32; epi relu(bn1) -> Wa
  lds_layer<1,4,2,1, 0,1, Dc,8, 4,32,64,64,32, 2><<<G32c2, TB, 0, stream>>>(
      W64a, we2, nul, nul, nul, nul, nul, nul, g1, b1, Wa);
  // ae1 3x3 (input >=0); epi relu(bn2) -> Wb
  lds_layer<1,3,1,1, 0,1, Dc,32, 4,32,32,32,32, 2><<<G32c2, TB, 0, stream>>>(
      Wa, ae1_w1, nul, nul, nul, nul, nul, nul, g2, b2, Wb);
  // ae1 1x1; epi Wa + val -> Wc
  lds_layer<1,1,1,0, 0,2, Dc,64, 4,32,32,32,32, 4><<<G32c4, TB, 0, stream>>>(
      Wb, ae1_w2, nul, nul, nul, Wa, nul, nul, nul, nul, Wc);
  // ae2 3x3: input relu(bn3(Wc)); epi relu(bn4) -> Wb
  lds_layer<1,3,1,1, 2,1, Dc,32, 4,32,32,32,32, 2><<<G32c2, TB, 0, stream>>>(
      Wc, ae2_w1, nul, g3, b3, nul, nul, nul, g4, b4, Wb);
  // ae2 1x1: epi bn5( bn3(Wc) + val ) -> out_ze
  lds_layer<1,1,1,0, 0,6, Dc,64, 4,32,32,32,32, 4><<<G32c4, TB, 0, stream>>>(
      Wb, ae2_w2, nul, nul, nul, Wc, g3, b3, g5, b5, out_ze);

  // ---------------- VQ ----------------
  vq_e2_kernel<<<2, 256, 0, stream>>>(embw, e2b);
  vq_kernel8<<<Bc * 1024 / 8, 256, 0, stream>>>(out_ze, embw, e2b, out_emb, out_am);

  // ---------------- decoder (z_q == emb numerically) ----------------
  // rd1 3x3: input relu(emb); epi relu(val) -> Wb
  lds_layer<0,3,1,1, 1,5, Dc,32, 4,32,32,32,32, 2><<<G32c2, TB, 0, stream>>>(
      out_emb, rd1_w1, rd1_b1, nul, nul, nul, nul, nul, nul, nul, Wb);
  // rd1 1x1: epi emb + val -> Wa
  lds_layer<0,1,1,0, 0,2, Dc,64, 4,32,32,32,32, 4><<<G32c4, TB, 0, stream>>>(
      Wb, rd1_w2, rd1_b2, nul, nul, out_emb, nul, nul, nul, nul, Wa);
  // rd2 3x3: input relu(bn6(Wa)); epi relu(val) -> Wb
  lds_layer<0,3,1,1, 2,5, Dc,32, 4,32,32,32,32, 2><<<G32c2, TB, 0, stream>>>(
      Wa, rd2_w1, rd2_b1, g6, b6, nul, nul, nul, nul, nul, Wb);
  // rd2 1x1: epi bn6(Wa) + val -> Wc
  lds_layer<0,1,1,0, 0,3, Dc,64, 4,32,32,32,32, 4><<<G32c4, TB, 0, stream>>>(
      Wb, rd2_w2, rd2_b2, nul, nul, Wa, g6, b6, nul, nul, Wc);

  up2x_kernel<<<nb(N64), TB, 0, stream>>>(Wc, W64a, Dc, 32, 32);
  // cd1 3x3 (64x64): epi relu(bn7(val)) -> W64b
  lds_layer<0,3,1,1, 0,1, Dc,16, 2,64,64,64,64, 8><<<G64c8, TB, 0, stream>>>(
      W64a, cd1_w, cd1_b, nul, nul, nul, nul, nul, g7, b7, W64b);

  // fused: up2x -> conv3x3(128->3) -> +bias -> tanh
  conv3x3_up_tanh_quad<<<nb(Bc * 3 * 64 * 64), TB, 0, stream>>>(W64b, cd2_w, cd2_b, out_y, 64, 64, 3);
}

// Round 13
// 876.540 us; speedup vs baseline: 1.2141x; 1.2141x over previous
//
#include <hip/hip_runtime.h>
#include <math.h>

// Problem constants
constexpr int Dc = 128;   // channels
constexpr int Kc = 512;   // codebook entries
constexpr int Bc = 8;     // batch

// ---------------------------------------------------------------------------
// LDS-tiled layer kernel: conv (ISADD=0) or AdderNet L1 (ISADD=1).
// Block = 256 threads = 4 waves; covers OUT_ROWS x WOUT pixels x 4*COBW output
// channels (COBW per wave, lane = 2-pixel group). Channel loop software-
// pipelined: chunk c+1 staged into REGISTERS (float4 global loads) before
// chunk c's compute, then written to LDS after the barrier.
// WLDS is a multiple of 4 so fragment reads vectorize: SPAN=6 -> b128+b64,
// SPAN=4 -> 2xb64, SPAN=2 -> b64 (alignment: col = pc*PW*STRIDE, row stride
// WLDS%4==0, lds alignas(16)). These patterns are minimum-phase on the 32
// banks. [R12 evidence: remaining SQ_LDS_BANK_CONFLICT is structural
// multi-phase counting of wide DS ops, not recoverable stall — layers are
// VALU-issue-bound at ~75% busy, ~2x useful-op instruction floor.]
//
// IT: 0 none, 1 relu, 2 relu(bn) with itG/itB
// EPI (val = -acc adder / acc conv): 1 relu(bn_o(val)); 2 res+val;
//   3 bn_r(res)+val; 5 relu(val); 6 bn_o(bn_r(res)+val)
template<int ISADD, int K, int STRIDE, int PAD, int IT, int EPI, int CIN, int CH,
         int OUT_ROWS, int WOUT, int WIN, int HIN, int HOUT, int COBW>
__global__ __launch_bounds__(256)
void lds_layer(const float* __restrict__ x, const float* __restrict__ w,
               const float* __restrict__ bias,
               const float* __restrict__ itG, const float* __restrict__ itB,
               const float* __restrict__ res,
               const float* __restrict__ rG, const float* __restrict__ rB,
               const float* __restrict__ oG, const float* __restrict__ oB,
               float* __restrict__ out) {
  constexpr int PW = 2;
  constexpr int KK = K * K;
  constexpr int SPAN = (PW - 1) * STRIDE + K;
  constexpr int IN_ROWS = (OUT_ROWS - 1) * STRIDE + K;
  constexpr int WPAD = (WOUT - 1) * STRIDE + K;
  constexpr int WLDS = (WPAD + 3) & ~3;         // mult of 4: aligned vector reads
  constexpr int PGW = WOUT / PW;
  static_assert(OUT_ROWS * PGW == 64, "one wave covers the pixel tile");
  constexpr int NCG = Dc / (4 * COBW);
  constexpr int NBAND = HOUT / OUT_ROWS;
  constexpr int W4 = WIN / 4;
  constexpr int NELEM4 = CH * IN_ROWS * W4;
  constexpr int NIT4 = (NELEM4 + 255) / 256;
  constexpr bool EXACT = (NELEM4 % 256) == 0;
  const float r15 = rsqrtf(1.0f + 1e-5f);

  __shared__ alignas(16) float lds[CH][IN_ROWS][WLDS];

  int tid = threadIdx.x;
  int gb = blockIdx.x;
  // XCD swizzle: cg outermost -> all channel-groups of a band share an XCD L2.
  int cg = gb / (Bc * NBAND);
  int rem = gb % (Bc * NBAND);
  int band = rem % NBAND;
  int b = rem / NBAND;
  int wv = __builtin_amdgcn_readfirstlane(tid >> 6);
  int lane = tid & 63;
  int co0 = cg * (4 * COBW) + wv * COBW;
  int pr = lane / PGW, pc = lane % PGW;
  int oh = band * OUT_ROWS + pr;
  int ow0 = pc * PW;
  int yi0 = band * OUT_ROWS * STRIDE - PAD;

  // zero LDS once: pad columns stay zero forever
  for (int e = tid; e < CH * IN_ROWS * WLDS; e += 256) ((float*)lds)[e] = 0.f;

  float acc[PW][COBW];
#pragma unroll
  for (int p = 0; p < PW; ++p)
#pragma unroll
    for (int j = 0; j < COBW; ++j)
      acc[p][j] = ISADD ? 0.f : bias[co0 + j];

  const float* xb = x + (long)b * CIN * HIN * WIN;
  float4 rbuf[NIT4];

  auto stage = [&](int c0) {
#pragma unroll
    for (int it = 0; it < NIT4; ++it) {
      int e = it * 256 + tid;
      if (!EXACT && e >= NELEM4) break;
      int c4 = e % W4;
      int r = (e / W4) % IN_ROWS;
      int ch = e / (W4 * IN_ROWS);
      int yi = yi0 + r;
      float4 v = make_float4(0.f, 0.f, 0.f, 0.f);
      if (yi >= 0 && yi < HIN) {
        v = *(const float4*)&xb[((long)(c0 + ch) * HIN + yi) * WIN + 4 * c4];
        if (IT == 1) {
          v.x = fmaxf(v.x, 0.f); v.y = fmaxf(v.y, 0.f);
          v.z = fmaxf(v.z, 0.f); v.w = fmaxf(v.w, 0.f);
        }
        if (IT == 2) {
          float sc = itG[c0 + ch] * r15, bc = itB[c0 + ch];
          v.x = fmaxf(fmaf(v.x, sc, bc), 0.f);
          v.y = fmaxf(fmaf(v.y, sc, bc), 0.f);
          v.z = fmaxf(fmaf(v.z, sc, bc), 0.f);
          v.w = fmaxf(fmaf(v.w, sc, bc), 0.f);
        }
      }
      rbuf[it] = v;
    }
  };
  auto towrite = [&]() {
#pragma unroll
    for (int it = 0; it < NIT4; ++it) {
      int e = it * 256 + tid;
      if (!EXACT && e >= NELEM4) break;
      int c4 = e % W4;
      int r = (e / W4) % IN_ROWS;
      int ch = e / (W4 * IN_ROWS);
      float* p = &lds[ch][r][4 * c4 + PAD];
      float4 v = rbuf[it];
      p[0] = v.x; p[1] = v.y; p[2] = v.z; p[3] = v.w;
    }
  };

  stage(0);
  for (int c0 = 0; c0 < CIN; c0 += CH) {
    __syncthreads();           // previous compute done before LDS overwrite
    towrite();
    __syncthreads();           // all writes visible
    if (c0 + CH < CIN) stage(c0 + CH);   // loads overlap compute below
    for (int ch = 0; ch < CH; ++ch) {
      float vbuf[K][SPAN];
#pragma unroll
      for (int kh = 0; kh < K; ++kh) {
        const float* rp0 = &lds[ch][pr * STRIDE + kh][ow0 * STRIDE];
        if constexpr (SPAN == 6 && (PW * STRIDE) % 4 == 0) {
          float4 a = *(const float4*)rp0;            // 16B aligned: col=4*pc
          float2 c2 = *(const float2*)(rp0 + 4);
          vbuf[kh][0] = a.x; vbuf[kh][1] = a.y; vbuf[kh][2] = a.z;
          vbuf[kh][3] = a.w; vbuf[kh][4] = c2.x; vbuf[kh][5] = c2.y;
        } else if constexpr (SPAN == 4 && (PW * STRIDE) % 2 == 0) {
          float2 a = *(const float2*)rp0;            // 8B aligned: col=2*pc
          float2 c2 = *(const float2*)(rp0 + 2);
          vbuf[kh][0] = a.x; vbuf[kh][1] = a.y;
          vbuf[kh][2] = c2.x; vbuf[kh][3] = c2.y;
        } else if constexpr (SPAN == 2 && (PW * STRIDE) % 2 == 0) {
          float2 a = *(const float2*)rp0;
          vbuf[kh][0] = a.x; vbuf[kh][1] = a.y;
        } else {
#pragma unroll
          for (int s = 0; s < SPAN; ++s) vbuf[kh][s] = rp0[s];
        }
      }
      const float* wc = w + ((long)co0 * CIN + (c0 + ch)) * KK;
#pragma unroll
      for (int kh = 0; kh < K; ++kh)
#pragma unroll
        for (int kw = 0; kw < K; ++kw)
#pragma unroll
          for (int j = 0; j < COBW; ++j) {
            float ww = wc[(long)j * CIN * KK + kh * K + kw];
#pragma unroll
            for (int p = 0; p < PW; ++p) {
              float v = vbuf[kh][p * STRIDE + kw];
              if (ISADD) acc[p][j] += fabsf(v - ww);
              else       acc[p][j] = fmaf(v, ww, acc[p][j]);
            }
          }
    }
  }

  // ---- epilogue ----
  long obase = ((long)(b * Dc + co0) * HOUT + oh) * WOUT + ow0;
  float* ob = out + obase;
  const float* rp = (EPI == 2 || EPI == 3 || EPI == 6) ? res + obase : nullptr;
  constexpr long hw = (long)HOUT * WOUT;
#pragma unroll
  for (int j = 0; j < COBW; ++j) {
    float og = 0.f, obb = 0.f, rg = 0.f, rbb = 0.f;
    if (EPI == 1 || EPI == 6) { og = oG[co0 + j] * r15; obb = oB[co0 + j]; }
    if (EPI == 3 || EPI == 6) { rg = rG[co0 + j] * r15; rbb = rB[co0 + j]; }
#pragma unroll
    for (int p = 0; p < PW; ++p) {
      float val = ISADD ? -acc[p][j] : acc[p][j];
      if (EPI == 1) val = fmaxf(fmaf(val, og, obb), 0.f);
      if (EPI == 2) val = rp[j * hw + p] + val;
      if (EPI == 3) val = fmaf(rp[j * hw + p], rg, rbb) + val;
      if (EPI == 5) val = fmaxf(val, 0.f);
      if (EPI == 6) val = fmaf(fmaf(rp[j * hw + p], rg, rbb) + val, og, obb);
      ob[j * hw + p] = val;
    }
  }
}

// ---------------------------------------------------------------------------
// 2x bilinear upsample, align_corners=False (clamped, weights 0.25/0.75)
__device__ __forceinline__ void up_coef(int p, int H, int& i0, int& i1, float& w0, float& w1) {
  int m = p >> 1;
  if ((p & 1) == 0) { i0 = (m > 0) ? m - 1 : 0; i1 = m; w0 = 0.25f; w1 = 0.75f; }
  else              { i0 = m; i1 = (m + 1 < H) ? m + 1 : H - 1; w0 = 0.75f; w1 = 0.25f; }
}

__global__ void up2x_kernel(const float* __restrict__ in, float* __restrict__ out,
                            int C, int H, int W) {
  int H2 = 2 * H, W2 = 2 * W;
  int i = blockIdx.x * blockDim.x + threadIdx.x;
  int total = Bc * C * H2 * W2;
  if (i >= total) return;
  int ow = i % W2; int t = i / W2;
  int oh = t % H2; t /= H2;
  int c = t % C; int b = t / C;
  int y0, y1, x0, x1; float wy0, wy1, wx0, wx1;
  up_coef(oh, H, y0, y1, wy0, wy1);
  up_coef(ow, W, x0, x1, wx0, wx1);
  const float* p = in + (b * C + c) * H * W;
  float v = wy0 * (wx0 * p[y0 * W + x0] + wx1 * p[y0 * W + x1])
          + wy1 * (wx0 * p[y1 * W + x0] + wx1 * p[y1 * W + x1]);
  out[i] = v;
}

// ---------------------------------------------------------------------------
// Fused: up2x -> conv3x3(128->Cout, pad=1) -> +bias -> tanh. One thread = one
// (b, co, 2x2 output quad).
__global__ __launch_bounds__(256)
void conv3x3_up_tanh_quad(const float* __restrict__ x, const float* __restrict__ w,
                          const float* __restrict__ bias, float* __restrict__ out,
                          int Hs, int Ws, int Cout) {
  constexpr int CIN = Dc;
  int H2 = 2 * Hs, W2 = 2 * Ws;
  int nq = Hs * Ws;
  int i = blockIdx.x * blockDim.x + threadIdx.x;
  int total = Bc * Cout * nq;
  if (i >= total) return;
  int q = i % nq; int t = i / nq;
  int co = t % Cout; int b = t / Cout;
  int n = q % Ws, m = q / Ws;
  int rows[3] = { (m > 0) ? m - 1 : 0, m, (m + 1 < Hs) ? m + 1 : Hs - 1 };
  int cols[3] = { (n > 0) ? n - 1 : 0, n, (n + 1 < Ws) ? n + 1 : Ws - 1 };
  float rv[4] = { (2 * m - 1 >= 0) ? 1.f : 0.f, 1.f, 1.f, (2 * m + 2 < H2) ? 1.f : 0.f };
  float cv[4] = { (2 * n - 1 >= 0) ? 1.f : 0.f, 1.f, 1.f, (2 * n + 2 < W2) ? 1.f : 0.f };
  float bco = bias[co];
  float acc[4] = { bco, bco, bco, bco };
  const float* xb = x + b * CIN * nq;
  const float* wb = w + co * CIN * 9;
  for (int c = 0; c < CIN; ++c) {
    const float* xc = xb + c * nq;
    float s[3][3];
#pragma unroll
    for (int a = 0; a < 3; ++a)
#pragma unroll
      for (int e = 0; e < 3; ++e) s[a][e] = xc[rows[a] * Ws + cols[e]];
    float rb[4][3];
#pragma unroll
    for (int e = 0; e < 3; ++e) {
      rb[0][e] = fmaf(0.75f, s[0][e], 0.25f * s[1][e]);
      rb[1][e] = fmaf(0.25f, s[0][e], 0.75f * s[1][e]);
      rb[2][e] = fmaf(0.75f, s[1][e], 0.25f * s[2][e]);
      rb[3][e] = fmaf(0.25f, s[1][e], 0.75f * s[2][e]);
    }
    float u[4][4];
#pragma unroll
    for (int di = 0; di < 4; ++di) {
      float rm = rv[di];
      u[di][0] = fmaf(0.75f, rb[di][0], 0.25f * rb[di][1]) * rm * cv[0];
      u[di][1] = fmaf(0.25f, rb[di][0], 0.75f * rb[di][1]) * rm * cv[1];
      u[di][2] = fmaf(0.75f, rb[di][1], 0.25f * rb[di][2]) * rm * cv[2];
      u[di][3] = fmaf(0.25f, rb[di][1], 0.75f * rb[di][2]) * rm * cv[3];
    }
    const float* wc = wb + c * 9;
#pragma unroll
    for (int kh = 0; kh < 3; ++kh)
#pragma unroll
      for (int kw = 0; kw < 3; ++kw) {
        float ww = wc[kh * 3 + kw];
        acc[0] = fmaf(u[kh][kw],         ww, acc[0]);
        acc[1] = fmaf(u[kh][kw + 1],     ww, acc[1]);
        acc[2] = fmaf(u[kh + 1][kw],     ww, acc[2]);
        acc[3] = fmaf(u[kh + 1][kw + 1], ww, acc[3]);
      }
  }
  float* ob = out + (b * Cout + co) * H2 * W2 + (2 * m) * W2 + 2 * n;
  ob[0] = tanhf(acc[0]);      ob[1] = tanhf(acc[1]);
  ob[W2] = tanhf(acc[2]);     ob[W2 + 1] = tanhf(acc[3]);
}

// ---------------------------------------------------------------------------
// VQ: precompute |E_k|^2 (d ascending, same as reference)
__global__ void vq_e2_kernel(const float* __restrict__ E, float* __restrict__ e2) {
  int k = blockIdx.x * blockDim.x + threadIdx.x;
  if (k >= Kc) return;
  float s = 0.f;
  for (int d = 0; d < Dc; ++d) { float v = E[d * Kc + k]; s += v * v; }
  e2[k] = s;
}

// VQ nearest-embedding: one 256-thread block per 8 spatial points.
__global__ __launch_bounds__(256)
void vq_kernel8(const float* __restrict__ z_e, const float* __restrict__ E,
                const float* __restrict__ e2,
                float* __restrict__ emb, float* __restrict__ argmin_out) {
  constexpr int HW = 1024;
  __shared__ float f[8][Dc];
  __shared__ float d2s[8][256];
  __shared__ int   ks[8][256];
  int tid = threadIdx.x;
  int n0 = blockIdx.x * 8;
  int b = n0 >> 10;
  int rem = n0 & 1023;
  const float* zb = z_e + (long)b * Dc * HW + rem;
#pragma unroll
  for (int i = 0; i < 4; ++i) {
    int e = i * 256 + tid;
    int p = e & 7, d = e >> 3;
    f[p][d] = zb[d * HW + p];
  }
  __syncthreads();
  float f2 = 0.f;
  if (tid < 8) {
    for (int d = 0; d < Dc; ++d) f2 += f[tid][d] * f[tid][d];
    d2s[tid][0] = f2;
  }
  __syncthreads();
  float f2v[8];
#pragma unroll
  for (int p = 0; p < 8; ++p) f2v[p] = d2s[p][0];
  __syncthreads();

  float best[8]; int bk[8];
#pragma unroll
  for (int p = 0; p < 8; ++p) { best[p] = 3.4e38f; bk[p] = 0; }
  for (int kk = tid; kk < Kc; kk += 256) {
    float dot[8];
#pragma unroll
    for (int p = 0; p < 8; ++p) dot[p] = 0.f;
    for (int d = 0; d < Dc; ++d) {
      float ed = E[d * Kc + kk];
#pragma unroll
      for (int p = 0; p < 8; ++p) dot[p] = fmaf(f[p][d], ed, dot[p]);
    }
    float e2k = e2[kk];
#pragma unroll
    for (int p = 0; p < 8; ++p) {
      float d2 = f2v[p] - 2.f * dot[p] + e2k;
      if (d2 < best[p] || (d2 == best[p] && kk < bk[p])) { best[p] = d2; bk[p] = kk; }
    }
  }
#pragma unroll
  for (int p = 0; p < 8; ++p) { d2s[p][tid] = best[p]; ks[p][tid] = bk[p]; }
  __syncthreads();
  for (int s = 128; s > 0; s >>= 1) {
    if (tid < s) {
#pragma unroll
      for (int p = 0; p < 8; ++p) {
        float ob = d2s[p][tid + s]; int ok = ks[p][tid + s];
        if (ob < d2s[p][tid] || (ob == d2s[p][tid] && ok < ks[p][tid])) {
          d2s[p][tid] = ob; ks[p][tid] = ok;
        }
      }
    }
    __syncthreads();
  }
  if (tid < 8) argmin_out[n0 + tid] = (float)ks[tid][0];
  float* eb = emb + (long)b * Dc * HW + rem;
#pragma unroll
  for (int i = 0; i < 4; ++i) {
    int e = i * 256 + tid;
    int p = e & 7, d = e >> 3;
    eb[d * HW + p] = E[d * Kc + ks[p][0]];
  }
}

// ---------------------------------------------------------------------------
extern "C" void kernel_launch(void* const* d_in, const int* in_sizes, int n_in,
                              void* d_out, int out_size, void* d_ws, size_t ws_size,
                              hipStream_t stream) {
  const float* x      = (const float*)d_in[0];
  const float* we1    = (const float*)d_in[1];
  const float* we2    = (const float*)d_in[2];
  const float* ae1_w1 = (const float*)d_in[3];
  const float* ae1_w2 = (const float*)d_in[4];
  const float* ae2_w1 = (const float*)d_in[5];
  const float* ae2_w2 = (const float*)d_in[6];
  const float* bn_g   = (const float*)d_in[7];   // [8,128]
  const float* bn_b   = (const float*)d_in[8];
  const float* embw   = (const float*)d_in[9];   // [128,512]
  const float* rd1_w1 = (const float*)d_in[10];
  const float* rd1_b1 = (const float*)d_in[11];
  const float* rd1_w2 = (const float*)d_in[12];
  const float* rd1_b2 = (const float*)d_in[13];
  const float* rd2_w1 = (const float*)d_in[14];
  const float* rd2_b1 = (const float*)d_in[15];
  const float* rd2_w2 = (const float*)d_in[16];
  const float* rd2_b2 = (const float*)d_in[17];
  const float* cd1_w  = (const float*)d_in[18];
  const float* cd1_b  = (const float*)d_in[19];
  const float* cd2_w  = (const float*)d_in[20];
  const float* cd2_b  = (const float*)d_in[21];

  const float* g0 = bn_g + 0 * Dc; const float* b0 = bn_b + 0 * Dc;
  const float* g1 = bn_g + 1 * Dc; const float* b1 = bn_b + 1 * Dc;
  const float* g2 = bn_g + 2 * Dc; const float* b2 = bn_b + 2 * Dc;
  const float* g3 = bn_g + 3 * Dc; const float* b3 = bn_b + 3 * Dc;
  const float* g4 = bn_g + 4 * Dc; const float* b4 = bn_b + 4 * Dc;
  const float* g5 = bn_g + 5 * Dc; const float* b5 = bn_b + 5 * Dc;
  const float* g6 = bn_g + 6 * Dc; const float* b6 = bn_b + 6 * Dc;
  const float* g7 = bn_g + 7 * Dc; const float* b7 = bn_b + 7 * Dc;

  // Workspace: two 64x64 buffers + three 32x32 buffers
  float* W64a = (float*)d_ws;            // [8,128,64,64]
  float* W64b = W64a + 4194304;          // [8,128,64,64]
  float* Wa   = W64b + 4194304;          // [8,128,32,32]
  float* Wb   = Wa + 1048576;
  float* Wc   = Wb + 1048576;
  float* e2b  = W64b;                    // 512 floats, free until cd1 writes W64b

  // Output layout: y | z_e | emb | argmin
  float* out_y   = (float*)d_out;        // 8*3*128*128
  float* out_ze  = out_y  + 393216;      // 8*128*32*32
  float* out_emb = out_ze + 1048576;
  float* out_am  = out_emb + 1048576;

  const int TB = 256;
  auto nb = [](int n) { return (n + 255) / 256; };
  const int N64 = Bc * Dc * 64 * 64;
  const float* nul = nullptr;

  // grids: NCG * Bc * NBAND  (empirical optimum configs, R9)
  const int G32c2 = 16 * Bc * 8;         // 1024 (32x32, OUT_ROWS=4 -> PW=2, COBW=2)
  const int G32c4 = 8 * Bc * 8;          // 512  (32x32, OUT_ROWS=4 -> PW=2, COBW=4)
  const int G64c4 = 8 * Bc * 32;         // 2048 (64x64, OUT_ROWS=2 -> PW=2, COBW=4)
  const int G64c8 = 4 * Bc * 32;         // 1024 (64x64, OUT_ROWS=2 -> PW=2, COBW=8)

  // ---------------- encoder ----------------
  // we1: adder 4x4 s2, 3ch (single chunk), 128->64; epi relu(bn0)
  lds_layer<1,4,2,1, 0,1, 3,3, 2,64,128,128,64, 4><<<G64c4, TB, 0, stream>>>(
      x, we1, nul, nul, nul, nul, nul, nul, g0, b0, W64a);
  // we2: adder 4x4 s2, 64->32; epi relu(bn1) -> Wa
  lds_layer<1,4,2,1, 0,1, Dc,8, 4,32,64,64,32, 2><<<G32c2, TB, 0, stream>>>(
      W64a, we2, nul, nul, nul, nul, nul, nul, g1, b1, Wa);
  // ae1 3x3 (input >=0); epi relu(bn2) -> Wb
  lds_layer<1,3,1,1, 0,1, Dc,32, 4,32,32,32,32, 2><<<G32c2, TB, 0, stream>>>(
      Wa, ae1_w1, nul, nul, nul, nul, nul, nul, g2, b2, Wb);
  // ae1 1x1; epi Wa + val -> Wc
  lds_layer<1,1,1,0, 0,2, Dc,64, 4,32,32,32,32, 4><<<G32c4, TB, 0, stream>>>(
      Wb, ae1_w2, nul, nul, nul, Wa, nul, nul, nul, nul, Wc);
  // ae2 3x3: input relu(bn3(Wc)); epi relu(bn4) -> Wb
  lds_layer<1,3,1,1, 2,1, Dc,32, 4,32,32,32,32, 2><<<G32c2, TB, 0, stream>>>(
      Wc, ae2_w1, nul, g3, b3, nul, nul, nul, g4, b4, Wb);
  // ae2 1x1: epi bn5( bn3(Wc) + val ) -> out_ze
  lds_layer<1,1,1,0, 0,6, Dc,64, 4,32,32,32,32, 4><<<G32c4, TB, 0, stream>>>(
      Wb, ae2_w2, nul, nul, nul, Wc, g3, b3, g5, b5, out_ze);

  // ---------------- VQ ----------------
  vq_e2_kernel<<<2, 256, 0, stream>>>(embw, e2b);
  vq_kernel8<<<Bc * 1024 / 8, 256, 0, stream>>>(out_ze, embw, e2b, out_emb, out_am);

  // ---------------- decoder (z_q == emb numerically) ----------------
  // rd1 3x3: input relu(emb); epi relu(val) -> Wb
  lds_layer<0,3,1,1, 1,5, Dc,32, 4,32,32,32,32, 2><<<G32c2, TB, 0, stream>>>(
      out_emb, rd1_w1, rd1_b1, nul, nul, nul, nul, nul, nul, nul, Wb);
  // rd1 1x1: epi emb + val -> Wa
  lds_layer<0,1,1,0, 0,2, Dc,64, 4,32,32,32,32, 4><<<G32c4, TB, 0, stream>>>(
      Wb, rd1_w2, rd1_b2, nul, nul, out_emb, nul, nul, nul, nul, Wa);
  // rd2 3x3: input relu(bn6(Wa)); epi relu(val) -> Wb
  lds_layer<0,3,1,1, 2,5, Dc,32, 4,32,32,32,32, 2><<<G32c2, TB, 0, stream>>>(
      Wa, rd2_w1, rd2_b1, g6, b6, nul, nul, nul, nul, nul, Wb);
  // rd2 1x1: epi bn6(Wa) + val -> Wc
  lds_layer<0,1,1,0, 0,3, Dc,64, 4,32,32,32,32, 4><<<G32c4, TB, 0, stream>>>(
      Wb, rd2_w2, rd2_b2, nul, nul, Wa, g6, b6, nul, nul, Wc);

  up2x_kernel<<<nb(N64), TB, 0, stream>>>(Wc, W64a, Dc, 32, 32);
  // cd1 3x3 (64x64): epi relu(bn7(val)) -> W64b
  lds_layer<0,3,1,1, 0,1, Dc,16, 2,64,64,64,64, 8><<<G64c8, TB, 0, stream>>>(
      W64a, cd1_w, cd1_b, nul, nul, nul, nul, nul, g7, b7, W64b);

  // fused: up2x -> conv3x3(128->3) -> +bias -> tanh
  conv3x3_up_tanh_quad<<<nb(Bc * 3 * 64 * 64), TB, 0, stream>>>(W64b, cd2_w, cd2_b, out_y, 64, 64, 3);
}